// Round 3
// baseline (236.163 us; speedup 1.0000x reference)
//
#include <hip/hip_runtime.h>
#include <math.h>

#define NL 12
#define NB 2
#define NT 2048
#define ND 2048
#define NC 4
#define NH 48
#define NBT (NB*NT)                 // 4096 tokens
#define BTD ((long)NBT*(long)ND)    // 8388608
#define TOK 8                       // tokens per block in dw_kernel

typedef float fx4 __attribute__((ext_vector_type(4)));

__device__ __forceinline__ float gelu_exact(float x) {
    return 0.5f * x * (1.0f + erff(x * 0.70710678118654752f));
}

// Kernel 1: dw[b,t,j] = (gelu(rms(x_cur) @ w1) @ w2)[j] + static_weight[j]
__global__ __launch_bounds__(256, 2)
void dw_kernel(const float* __restrict__ xs,
               const float* __restrict__ w1,
               const float* __restrict__ w2,
               const float* __restrict__ sw,
               float* __restrict__ dw_out) {
    __shared__ float xls[TOK][ND];      // 64 KB: 8 token rows of x_current
    __shared__ float rinv_s[TOK];
    __shared__ float y_s[TOK][NH];
    const int tid  = threadIdx.x;
    const int wave = tid >> 6;
    const int lane = tid & 63;

    const float* xcur = xs + (long)(NL - 1) * BTD + (long)blockIdx.x * TOK * ND;
    const float4* src = (const float4*)xcur;
    float4* dst = (float4*)&xls[0][0];
    #pragma unroll
    for (int i = 0; i < (TOK * ND / 4) / 256; ++i)
        dst[tid + i * 256] = src[tid + i * 256];
    __syncthreads();

    #pragma unroll
    for (int tt = 0; tt < 2; ++tt) {
        const int tok = wave * 2 + tt;
        float ss = 0.f;
        for (int d = lane; d < ND; d += 64) { float v = xls[tok][d]; ss += v * v; }
        #pragma unroll
        for (int off = 32; off; off >>= 1) ss += __shfl_xor(ss, off);
        if (lane == 0) rinv_s[tok] = rsqrtf(ss * (1.0f / ND) + 1e-6f);
    }
    __syncthreads();

    float rv[TOK];
    #pragma unroll
    for (int t = 0; t < TOK; ++t) rv[t] = rinv_s[t];

    float acc[TOK][12];
    #pragma unroll
    for (int t = 0; t < TOK; ++t)
        #pragma unroll
        for (int j = 0; j < 12; ++j) acc[t][j] = 0.f;

    const int h0 = wave * 12;
    for (int d = lane; d < ND; d += 64) {
        const float* wrow = w1 + (long)d * NH + h0;
        const float4 wA = *(const float4*)(wrow);
        const float4 wB = *(const float4*)(wrow + 4);
        const float4 wC = *(const float4*)(wrow + 8);
        #pragma unroll
        for (int t = 0; t < TOK; ++t) {
            const float xv = xls[t][d] * rv[t];
            acc[t][0]  += xv * wA.x; acc[t][1]  += xv * wA.y;
            acc[t][2]  += xv * wA.z; acc[t][3]  += xv * wA.w;
            acc[t][4]  += xv * wB.x; acc[t][5]  += xv * wB.y;
            acc[t][6]  += xv * wB.z; acc[t][7]  += xv * wB.w;
            acc[t][8]  += xv * wC.x; acc[t][9]  += xv * wC.y;
            acc[t][10] += xv * wC.z; acc[t][11] += xv * wC.w;
        }
    }
    #pragma unroll
    for (int t = 0; t < TOK; ++t)
        #pragma unroll
        for (int j = 0; j < 12; ++j) {
            float v = acc[t][j];
            #pragma unroll
            for (int off = 32; off; off >>= 1) v += __shfl_xor(v, off);
            acc[t][j] = v;
        }
    if (lane == 0) {
        #pragma unroll
        for (int t = 0; t < TOK; ++t)
            #pragma unroll
            for (int j = 0; j < 12; ++j)
                y_s[t][h0 + j] = acc[t][j];
    }
    __syncthreads();

    for (int i = tid; i < TOK * NH; i += 256) {
        float* p = &y_s[0][0];
        p[i] = gelu_exact(p[i]);
    }
    __syncthreads();

    for (int i = tid; i < TOK * NH; i += 256) {
        const int tok = i / NH;
        const int j   = i - tok * NH;
        float z = sw[j];
        #pragma unroll
        for (int h = 0; h < NH; ++h) z += y_s[tok][h] * w2[h * NH + j];
        dw_out[((long)blockIdx.x * TOK + tok) * NH + j] = z;
    }
}

// Kernel 2 v2: 512 threads, 1 fx4 per layer per thread, 2 barriers,
// nontemporal streams for xs/out so L2 keeps the scales.
__global__ __launch_bounds__(512, 4)
void agg_kernel(const float* __restrict__ xs,
                const float* __restrict__ dw,
                const float* __restrict__ pre_scales,
                const float* __restrict__ post_scales,
                float* __restrict__ out) {
    const int tid  = threadIdx.x;
    const int wave = tid >> 6;
    const int lane = tid & 63;
    const long token = blockIdx.x;
    const long voff = token * ND + (long)tid * 4;   // element offset in one layer plane

    __shared__ float dw_s[NC * NL];
    __shared__ float red[8][NL];
    __shared__ float red2[8][NC];

    if (tid < NC * NL) dw_s[tid] = dw[token * (NC * NL) + tid];

    // 12 independent nontemporal streams, issued up front
    fx4 x[NL];
    #pragma unroll
    for (int l = 0; l < NL; ++l)
        x[l] = __builtin_nontemporal_load((const fx4*)(xs + (long)l * BTD + voff));

    // per-layer wave-partial sumsq
    #pragma unroll
    for (int l = 0; l < NL; ++l) {
        float v = x[l].x*x[l].x + x[l].y*x[l].y + x[l].z*x[l].z + x[l].w*x[l].w;
        #pragma unroll
        for (int off = 32; off; off >>= 1) v += __shfl_xor(v, off);
        if (lane == 0) red[wave][l] = v;
    }
    __syncthreads();   // also covers dw_s visibility

    // every thread folds the 8 wave partials itself (no extra barrier)
    float rvv[NL];
    {
        float s[NL];
        #pragma unroll
        for (int l = 0; l < NL; ++l) s[l] = 0.f;
        #pragma unroll
        for (int w = 0; w < 8; ++w) {
            const fx4 r0 = *(const fx4*)&red[w][0];
            const fx4 r1 = *(const fx4*)&red[w][4];
            const fx4 r2 = *(const fx4*)&red[w][8];
            s[0] += r0.x; s[1]  += r0.y; s[2]  += r0.z; s[3]  += r0.w;
            s[4] += r1.x; s[5]  += r1.y; s[6]  += r1.z; s[7]  += r1.w;
            s[8] += r2.x; s[9]  += r2.y; s[10] += r2.z; s[11] += r2.w;
        }
        #pragma unroll
        for (int l = 0; l < NL; ++l) rvv[l] = rsqrtf(s[l] * (1.0f / ND) + 1e-6f);
    }

    // aggregate 4 ways
    fx4 acc[NC];
    #pragma unroll
    for (int c = 0; c < NC; ++c) acc[c] = (fx4)(0.f);

    #pragma unroll
    for (int l = 0; l < NL; ++l) {
        const fx4 p = *(const fx4*)(pre_scales + (long)l * ND + (long)tid * 4);
        const float rv = rvv[l];
        const fx4 xn = x[l] * rv * p;
        #pragma unroll
        for (int c = 0; c < NC; ++c) {
            const float w = dw_s[c * NL + l];
            acc[c] += w * xn;
        }
    }

    // per-way sumsq
    #pragma unroll
    for (int c = 0; c < NC; ++c) {
        float v = acc[c].x*acc[c].x + acc[c].y*acc[c].y
                + acc[c].z*acc[c].z + acc[c].w*acc[c].w;
        #pragma unroll
        for (int off = 32; off; off >>= 1) v += __shfl_xor(v, off);
        if (lane == 0) red2[wave][c] = v;
    }
    __syncthreads();

    float r2v[NC];
    {
        float s[NC];
        #pragma unroll
        for (int c = 0; c < NC; ++c) s[c] = 0.f;
        #pragma unroll
        for (int w = 0; w < 8; ++w) {
            const fx4 r = *(const fx4*)&red2[w][0];
            s[0] += r.x; s[1] += r.y; s[2] += r.z; s[3] += r.w;
        }
        #pragma unroll
        for (int c = 0; c < NC; ++c) r2v[c] = rsqrtf(s[c] * (1.0f / ND) + 1e-6f);
    }

    // out = rms(agg) * post_scales + x_current   (x[NL-1] is x_current)
    #pragma unroll
    for (int c = 0; c < NC; ++c) {
        const fx4 q = *(const fx4*)(post_scales + (long)c * ND + (long)tid * 4);
        const float r2 = r2v[c];
        const fx4 o = acc[c] * r2 * q + x[NL-1];
        __builtin_nontemporal_store(o, (fx4*)(out + (long)c * BTD + voff));
    }
}

extern "C" void kernel_launch(void* const* d_in, const int* in_sizes, int n_in,
                              void* d_out, int out_size, void* d_ws, size_t ws_size,
                              hipStream_t stream) {
    const float* xs   = (const float*)d_in[0];
    const float* w1   = (const float*)d_in[1];
    const float* w2   = (const float*)d_in[2];
    const float* sw   = (const float*)d_in[3];
    const float* pre  = (const float*)d_in[4];
    const float* post = (const float*)d_in[5];
    float* out   = (float*)d_out;
    float* dw_ws = (float*)d_ws;   // 4096*48 floats = 786 KB

    dw_kernel<<<NBT / TOK, 256, 0, stream>>>(xs, w1, w2, sw, dw_ws);
    agg_kernel<<<NBT, 512, 0, stream>>>(xs, dw_ws, pre, post, out);
}

// Round 4
// 206.801 us; speedup vs baseline: 1.1420x; 1.1420x over previous
//
#include <hip/hip_runtime.h>
#include <math.h>

#define NL 12
#define NB 2
#define NT 2048
#define ND 2048
#define NC 4
#define NH 48
#define NBT (NB*NT)                 // 4096 tokens
#define BTD ((long)NBT*(long)ND)    // 8388608
#define TOK 8                       // tokens per block in dw_kernel

typedef float fx4 __attribute__((ext_vector_type(4)));

__device__ __forceinline__ float gelu_exact(float x) {
    return 0.5f * x * (1.0f + erff(x * 0.70710678118654752f));
}

// Kernel 1: dw[b,t,j] = (gelu(rms(x_cur) @ w1) @ w2)[j] + static_weight[j]
__global__ __launch_bounds__(256, 2)
void dw_kernel(const float* __restrict__ xs,
               const float* __restrict__ w1,
               const float* __restrict__ w2,
               const float* __restrict__ sw,
               float* __restrict__ dw_out) {
    __shared__ float xls[TOK][ND];      // 64 KB: 8 token rows of x_current
    __shared__ float rinv_s[TOK];
    __shared__ float y_s[TOK][NH];
    const int tid  = threadIdx.x;
    const int wave = tid >> 6;
    const int lane = tid & 63;

    const float* xcur = xs + (long)(NL - 1) * BTD + (long)blockIdx.x * TOK * ND;
    const float4* src = (const float4*)xcur;
    float4* dst = (float4*)&xls[0][0];
    #pragma unroll
    for (int i = 0; i < (TOK * ND / 4) / 256; ++i)
        dst[tid + i * 256] = src[tid + i * 256];
    __syncthreads();

    #pragma unroll
    for (int tt = 0; tt < 2; ++tt) {
        const int tok = wave * 2 + tt;
        float ss = 0.f;
        for (int d = lane; d < ND; d += 64) { float v = xls[tok][d]; ss += v * v; }
        #pragma unroll
        for (int off = 32; off; off >>= 1) ss += __shfl_xor(ss, off);
        if (lane == 0) rinv_s[tok] = rsqrtf(ss * (1.0f / ND) + 1e-6f);
    }
    __syncthreads();

    float rv[TOK];
    #pragma unroll
    for (int t = 0; t < TOK; ++t) rv[t] = rinv_s[t];

    float acc[TOK][12];
    #pragma unroll
    for (int t = 0; t < TOK; ++t)
        #pragma unroll
        for (int j = 0; j < 12; ++j) acc[t][j] = 0.f;

    const int h0 = wave * 12;
    for (int d = lane; d < ND; d += 64) {
        const float* wrow = w1 + (long)d * NH + h0;
        const float4 wA = *(const float4*)(wrow);
        const float4 wB = *(const float4*)(wrow + 4);
        const float4 wC = *(const float4*)(wrow + 8);
        #pragma unroll
        for (int t = 0; t < TOK; ++t) {
            const float xv = xls[t][d] * rv[t];
            acc[t][0]  += xv * wA.x; acc[t][1]  += xv * wA.y;
            acc[t][2]  += xv * wA.z; acc[t][3]  += xv * wA.w;
            acc[t][4]  += xv * wB.x; acc[t][5]  += xv * wB.y;
            acc[t][6]  += xv * wB.z; acc[t][7]  += xv * wB.w;
            acc[t][8]  += xv * wC.x; acc[t][9]  += xv * wC.y;
            acc[t][10] += xv * wC.z; acc[t][11] += xv * wC.w;
        }
    }
    #pragma unroll
    for (int t = 0; t < TOK; ++t)
        #pragma unroll
        for (int j = 0; j < 12; ++j) {
            float v = acc[t][j];
            #pragma unroll
            for (int off = 32; off; off >>= 1) v += __shfl_xor(v, off);
            acc[t][j] = v;
        }
    if (lane == 0) {
        #pragma unroll
        for (int t = 0; t < TOK; ++t)
            #pragma unroll
            for (int j = 0; j < 12; ++j)
                y_s[t][h0 + j] = acc[t][j];
    }
    __syncthreads();

    for (int i = tid; i < TOK * NH; i += 256) {
        float* p = &y_s[0][0];
        p[i] = gelu_exact(p[i]);
    }
    __syncthreads();

    for (int i = tid; i < TOK * NH; i += 256) {
        const int tok = i / NH;
        const int j   = i - tok * NH;
        float z = sw[j];
        #pragma unroll
        for (int h = 0; h < NH; ++h) z += y_s[tok][h] * w2[h * NH + j];
        dw_out[((long)blockIdx.x * TOK + tok) * NH + j] = z;
    }
}

// Kernel 2 v3: 512 threads, 1 fx4 per layer per thread, 2 barriers.
// Plain loads (keep L3 replay hits); nontemporal ONLY on out stores.
// launch_bounds(512,3): ~170 VGPR cap -> no spill, 3 blocks/CU stagger.
__global__ __launch_bounds__(512, 3)
void agg_kernel(const float* __restrict__ xs,
                const float* __restrict__ dw,
                const float* __restrict__ pre_scales,
                const float* __restrict__ post_scales,
                float* __restrict__ out) {
    const int tid  = threadIdx.x;
    const int wave = tid >> 6;
    const int lane = tid & 63;
    const long token = blockIdx.x;
    const long voff = token * ND + (long)tid * 4;   // element offset in one layer plane

    __shared__ float dw_s[NC * NL];
    __shared__ float red[8][NL];
    __shared__ float red2[8][NC];

    if (tid < NC * NL) dw_s[tid] = dw[token * (NC * NL) + tid];

    // 12 independent streams, issued up front
    fx4 x[NL];
    #pragma unroll
    for (int l = 0; l < NL; ++l)
        x[l] = *(const fx4*)(xs + (long)l * BTD + voff);

    // per-layer wave-partial sumsq
    #pragma unroll
    for (int l = 0; l < NL; ++l) {
        float v = x[l].x*x[l].x + x[l].y*x[l].y + x[l].z*x[l].z + x[l].w*x[l].w;
        #pragma unroll
        for (int off = 32; off; off >>= 1) v += __shfl_xor(v, off);
        if (lane == 0) red[wave][l] = v;
    }
    __syncthreads();   // also covers dw_s visibility

    // every thread folds the 8 wave partials itself (no extra barrier)
    float rvv[NL];
    {
        float s[NL];
        #pragma unroll
        for (int l = 0; l < NL; ++l) s[l] = 0.f;
        #pragma unroll
        for (int w = 0; w < 8; ++w) {
            const fx4 r0 = *(const fx4*)&red[w][0];
            const fx4 r1 = *(const fx4*)&red[w][4];
            const fx4 r2 = *(const fx4*)&red[w][8];
            s[0] += r0.x; s[1]  += r0.y; s[2]  += r0.z; s[3]  += r0.w;
            s[4] += r1.x; s[5]  += r1.y; s[6]  += r1.z; s[7]  += r1.w;
            s[8] += r2.x; s[9]  += r2.y; s[10] += r2.z; s[11] += r2.w;
        }
        #pragma unroll
        for (int l = 0; l < NL; ++l) rvv[l] = rsqrtf(s[l] * (1.0f / ND) + 1e-6f);
    }

    // aggregate 4 ways
    fx4 acc[NC];
    #pragma unroll
    for (int c = 0; c < NC; ++c) acc[c] = (fx4)(0.f);

    #pragma unroll
    for (int l = 0; l < NL; ++l) {
        const fx4 p = *(const fx4*)(pre_scales + (long)l * ND + (long)tid * 4);
        const float rv = rvv[l];
        const fx4 xn = x[l] * rv * p;
        #pragma unroll
        for (int c = 0; c < NC; ++c) {
            const float w = dw_s[c * NL + l];
            acc[c] += w * xn;
        }
    }

    // per-way sumsq
    #pragma unroll
    for (int c = 0; c < NC; ++c) {
        float v = acc[c].x*acc[c].x + acc[c].y*acc[c].y
                + acc[c].z*acc[c].z + acc[c].w*acc[c].w;
        #pragma unroll
        for (int off = 32; off; off >>= 1) v += __shfl_xor(v, off);
        if (lane == 0) red2[wave][c] = v;
    }
    __syncthreads();

    float r2v[NC];
    {
        float s[NC];
        #pragma unroll
        for (int c = 0; c < NC; ++c) s[c] = 0.f;
        #pragma unroll
        for (int w = 0; w < 8; ++w) {
            const fx4 r = *(const fx4*)&red2[w][0];
            s[0] += r.x; s[1] += r.y; s[2] += r.z; s[3] += r.w;
        }
        #pragma unroll
        for (int c = 0; c < NC; ++c) r2v[c] = rsqrtf(s[c] * (1.0f / ND) + 1e-6f);
    }

    // out = rms(agg) * post_scales + x_current   (x[NL-1] is x_current)
    #pragma unroll
    for (int c = 0; c < NC; ++c) {
        const fx4 q = *(const fx4*)(post_scales + (long)c * ND + (long)tid * 4);
        const float r2 = r2v[c];
        const fx4 o = acc[c] * r2 * q + x[NL-1];
        __builtin_nontemporal_store(o, (fx4*)(out + (long)c * BTD + voff));
    }
}

extern "C" void kernel_launch(void* const* d_in, const int* in_sizes, int n_in,
                              void* d_out, int out_size, void* d_ws, size_t ws_size,
                              hipStream_t stream) {
    const float* xs   = (const float*)d_in[0];
    const float* w1   = (const float*)d_in[1];
    const float* w2   = (const float*)d_in[2];
    const float* sw   = (const float*)d_in[3];
    const float* pre  = (const float*)d_in[4];
    const float* post = (const float*)d_in[5];
    float* out   = (float*)d_out;
    float* dw_ws = (float*)d_ws;   // 4096*48 floats = 786 KB

    dw_kernel<<<NBT / TOK, 256, 0, stream>>>(xs, w1, w2, sw, dw_ws);
    agg_kernel<<<NBT, 512, 0, stream>>>(xs, dw_ws, pre, post, out);
}